// Round 9
// baseline (154.659 us; speedup 1.0000x reference)
//
#include <hip/hip_runtime.h>

// Correlation layer: in1,in2 [8,256,128,128] f32 -> out [8,81,128,128] f32
// out[b, dy*9+dx, y, x] = mean_c in1[b,c,y,x] * in2pad[b,c,y+dy,x+dx], pad=4
//
// v9 = v8 geometry (tile 16x16, staged 24x24, 16-ch half-steps) with 16B DMA
// granules (pad=4 aligns exactly -> no edge shift; known-good lane stride).
// 2304 granules/step = 36 instr: waves 0-3 issue 5, waves 4-7 issue 4;
// per-wave keep-counts vmcnt(13)/vmcnt(12). v6's two-rendezvous schedule.
// MFMA: 2 rows/wave, tile0 18 + tile1 10 (2 dy packed) per 32-ch chunk.

#define B_   8
#define C_   256
#define H_   128
#define W_   128
#define ND   9
#define TY   16
#define TW   16
#define CS   (H_ * W_)
#define NST  16                  // 16-ch steps per tile
#define NDMAX 5
#define SB   9216                // floats per S half-buffer (16*24*24)
#define SBY  36864
#define FBsh 18432               // shorts per F chunk buffer (4*24*24*8)
#define FBY  36864
#define EPOFF (2 * SBY + 2 * FBY)         // 147456
#define LDS_TOTAL (EPOFF + 12288)         // 159744

typedef short v8s __attribute__((ext_vector_type(8)));
typedef float v4f __attribute__((ext_vector_type(4)));

__device__ __forceinline__ unsigned short f2bf(float f) {
    union { float f; unsigned u; } v; v.f = f;
    return (unsigned short)((v.u + 0x7FFFu + ((v.u >> 16) & 1u)) >> 16);
}

__device__ __forceinline__ void dma16(const float* g, void* lds) {
    __builtin_amdgcn_global_load_lds(
        (const __attribute__((address_space(1))) void*)g,
        (__attribute__((address_space(3))) void*)lds, 16, 0, 0);
}

#define FENCE()     asm volatile("" ::: "memory")
// per-wave keep-count: retire G(s+1) (13/12 ops), keep G(s+2) in flight
#define WAITK_BAR() do {                                                      \
        if (w < 4) asm volatile("s_waitcnt vmcnt(13)\n\ts_barrier" ::: "memory"); \
        else       asm volatile("s_waitcnt vmcnt(12)\n\ts_barrier" ::: "memory"); \
    } while (0)
#define WAITV0_BAR() asm volatile("s_waitcnt vmcnt(0)\n\ts_barrier" ::: "memory")
#define LGKM0_BAR()  asm volatile("s_waitcnt lgkmcnt(0)\n\ts_barrier" ::: "memory")
#define LGKM0()      asm volatile("s_waitcnt lgkmcnt(0)" ::: "memory")

__global__ __launch_bounds__(512, 2)
void corr_mfma_kernel(const float* __restrict__ in1,
                      const float* __restrict__ in2,
                      float* __restrict__ out) {
    extern __shared__ __align__(16) char ldsbase[];
    float* S  = (float*)ldsbase;               // S[2][16ch][24r][24j] f32 halves
    short* F  = (short*)(ldsbase + 2 * SBY);   // F[2][4kb][24r][24j][8e] bf16
    float* EP = (float*)(ldsbase + EPOFF);     // 8 waves x 384 f32

    const int tid  = threadIdx.x;
    const int lane = tid & 63;
    const int w    = tid >> 6;

    const int lin = blockIdx.x;                // 512 blocks
    const int b   = lin & 7;                   // batch == XCD
    const int idx = lin >> 3;                  // 0..63
    const int x0  = (idx & 7) * TW;
    const int y0  = (idx >> 3) * TY;

    const int i_px = lane & 15;
    const int kb   = lane >> 4;

    // ---- DMA descriptors: 16B granules; waves 0-3: 5 instr, 4-7: 4 ----
    const float* dsrc[NDMAX];
    int ddst[NDMAX];
    #pragma unroll
    for (int t = 0; t < NDMAX; ++t) {
        if (w >= 4 && t >= 4) { dsrc[t] = in2; ddst[t] = 0; continue; }
        const int q   = (w < 4) ? (w * 5 + t) : (20 + (w - 4) * 4 + t); // 0..35
        const int g   = q * 64 + lane;         // 0..2303
        const int ccl = g / 144;               // channel within 16-ch step
        const int rem = g % 144;
        const int r   = rem / 6;               // staged row 0..23
        const int jg  = rem % 6;               // 4-col granule
        int gy = y0 - 4 + r;
        int gx = x0 - 4 + jg * 4;
        gy = gy < 0 ? 0 : (gy > H_ - 1 ? H_ - 1 : gy);
        gx = gx < 0 ? 0 : (gx > W_ - 4 ? W_ - 4 : gx);   // pad=4 == granule: exact
        dsrc[t] = in2 + ((long)(b * C_) + ccl) * CS + gy * W_ + gx;
        ddst[t] = q * 1024;                    // wave-uniform; HW adds lane*16
    }

    // ---- convert descriptors: 1152 items/step -> it 0..2 (it2: tid<128) ----
    int csoff[3], cfoff[3];
    bool cval[3];
    #pragma unroll
    for (int it = 0; it < 3; ++it) {
        const int s2  = (tid + it * 512) % 1152;
        const int kbl = s2 / 576;              // 0..1
        const int rem = s2 % 576;
        const int r   = rem / 24;
        const int j   = rem % 24;
        csoff[it] = kbl * 4608 + rem;          // + e*576
        cfoff[it] = (kbl * 576 + rem) * 8;
        cval[it]  = ((unsigned)(y0 - 4 + r) < (unsigned)H_) &&
                    ((unsigned)(x0 - 4 + j) < (unsigned)W_);
    }

    const float* p1w =
        in1 + ((long)b * C_ + kb * 8) * CS + (long)(y0 + 2 * w) * W_ + x0 + i_px;

    v4f acc0[2][ND];
    v4f acc1[2][5];
    #pragma unroll
    for (int rw = 0; rw < 2; ++rw) {
        #pragma unroll
        for (int d = 0; d < ND; ++d) acc0[rw][d] = (v4f)0.0f;
        #pragma unroll
        for (int p = 0; p < 5; ++p)  acc1[rw][p] = (v4f)0.0f;
    }
    float a_buf[2][2][8];                      // [chunk&1][row][e]
    v8s afrag[2];

    // G(s) = DMA (step s -> S[s&1]) + 8 A-loads (chunk s/2, row s&1)
#define ISSUE_G(s_) do {                                                     \
        const long so = (long)(s_) * 16 * CS;                                \
        _Pragma("unroll")                                                    \
        for (int t = 0; t < NDMAX; ++t)                                      \
            if (w < 4 || t < 4)                                              \
                dma16(dsrc[t] + so, (char*)S + ((s_) & 1) * SBY + ddst[t]);  \
        const long ao = (long)((s_) >> 1) * 32 * CS + ((s_) & 1) * W_;       \
        _Pragma("unroll")                                                    \
        for (int e = 0; e < 8; ++e)                                          \
            a_buf[((s_) >> 1) & 1][(s_) & 1][e] = p1w[ao + (long)e * CS];    \
        FENCE();                                                             \
    } while (0)

#define CONVERT(s_) do {                                                     \
        const int sb = ((s_) & 1) * SB;                                      \
        const int fb = (((s_) >> 1) & 1) * FBsh + ((s_) & 1) * 9216;         \
        _Pragma("unroll")                                                    \
        for (int it = 0; it < 3; ++it) {                                     \
            if (it < 2 || tid < 128) {                                       \
                v8s pk;                                                      \
                _Pragma("unroll")                                            \
                for (int e = 0; e < 8; ++e)                                  \
                    pk[e] = (short)f2bf(S[sb + csoff[it] + e * 576]);        \
                if (!cval[it]) pk = (v8s)0;                                  \
                *(v8s*)&F[fb + cfoff[it]] = pk;                              \
            }                                                                \
        }                                                                    \
    } while (0)

#define AFRAG_CVT(c_) do {                                                   \
        _Pragma("unroll")                                                    \
        for (int rw = 0; rw < 2; ++rw)                                       \
            _Pragma("unroll")                                                \
            for (int e = 0; e < 8; ++e)                                      \
                afrag[rw][e] = (short)f2bf(a_buf[(c_) & 1][rw][e]);          \
    } while (0)

    // ---- prologue ----
    ISSUE_G(0);
    ISSUE_G(1);
    WAITK_BAR();                   // all waves' step-0 DMA landed; G(1) in flight
    CONVERT(0);
    LGKM0_BAR();                   // F[0].lo visible; S[0] free

    // ---- main: 16 steps ----
    #pragma unroll
    for (int s = 0; s < NST; ++s) {
        // region A: issue step s+2; MFMA chunk s>>1 on odd steps
        if (s + 2 < NST) ISSUE_G(s + 2);

        if (s & 1) {
            const int c = s >> 1;
            const short* Fb = F + (c & 1) * FBsh;
            #pragma unroll
            for (int u = 0; u < 10; ++u) {     // tile0: rolling over r=2w+u
                const v8s f = *(const v8s*)&Fb[(kb * 576 + (2 * w + u) * 24 + i_px) * 8];
                if (u < 9)
                    acc0[0][u] = __builtin_amdgcn_mfma_f32_16x16x32_bf16(
                        afrag[0], f, acc0[0][u], 0, 0, 0);
                if (u > 0)
                    acc0[1][u - 1] = __builtin_amdgcn_mfma_f32_16x16x32_bf16(
                        afrag[1], f, acc0[1][u - 1], 0, 0, 0);
            }
            const int hi = i_px >> 3, j1 = 16 + (i_px & 7);
            #pragma unroll
            for (int u = 0; u < 10; ++u) {     // tile1 packed: 2 dy per MFMA
                int r = 2 * w + hi + u;
                if (r > 23) r = 23;            // (rw1,P4,hi1) garbage, unused
                const v8s f = *(const v8s*)&Fb[(kb * 576 + r * 24 + j1) * 8];
                if ((u & 1) == 0)
                    acc1[0][u >> 1] = __builtin_amdgcn_mfma_f32_16x16x32_bf16(
                        afrag[0], f, acc1[0][u >> 1], 0, 0, 0);
                else
                    acc1[1][u >> 1] = __builtin_amdgcn_mfma_f32_16x16x32_bf16(
                        afrag[1], f, acc1[1][u >> 1], 0, 0, 0);
            }
        }

        // rendezvous: retire G(s+1), keep G(s+2) in flight
        if (s + 2 < NST)       { WAITK_BAR(); }
        else if (s == NST - 2) { WAITV0_BAR(); }

        // region B: convert step s+1; afrag for chunk s/2 on even steps
        if (s < NST - 1) {
            CONVERT(s + 1);
            if ((s & 1) == 0) AFRAG_CVT(s >> 1);
            LGKM0_BAR();
        }
    }

    // ---- epilogue: 2 rows/wave, wave-private EP scratch ----
    float* epw = EP + w * 384;
    const int g4 = lane >> 4;
    #pragma unroll
    for (int rw = 0; rw < 2; ++rw) {
        const int orow = y0 + 2 * w + rw;
        #pragma unroll
        for (int dy = 0; dy < ND; ++dy) {
            #pragma unroll
            for (int q = 0; q < 4; ++q)
                epw[(g4 * 4 + q) * 24 + i_px] = acc0[rw][dy][q];
            if ((i_px >> 3) == (dy & 1)) {
                #pragma unroll
                for (int q = 0; q < 4; ++q)
                    epw[(g4 * 4 + q) * 24 + 16 + (i_px & 7)] = acc1[rw][dy >> 1][q];
            }
            LGKM0();
            #pragma unroll
            for (int rep = 0; rep < 3; ++rep) {
                const int dx = g4 + rep * 4;
                if (dx < 9) {
                    const float v = epw[i_px * 24 + i_px + dx] * (1.0f / 256.0f);
                    out[(((long)b * 81 + dy * 9 + dx) * H_ + orow) * W_ + x0 + i_px] = v;
                }
            }
            LGKM0();
        }
    }
#undef ISSUE_G
#undef CONVERT
#undef AFRAG_CVT
}

extern "C" void kernel_launch(void* const* d_in, const int* in_sizes, int n_in,
                              void* d_out, int out_size, void* d_ws, size_t ws_size,
                              hipStream_t stream) {
    const float* in1 = (const float*)d_in[0];
    const float* in2 = (const float*)d_in[1];
    float* outp      = (float*)d_out;
    (void)hipFuncSetAttribute((const void*)corr_mfma_kernel,
                              hipFuncAttributeMaxDynamicSharedMemorySize,
                              LDS_TOTAL);
    corr_mfma_kernel<<<512, 512, LDS_TOTAL, stream>>>(in1, in2, outp);
}

// Round 10
// 90.726 us; speedup vs baseline: 1.7047x; 1.7047x over previous
//
#include <hip/hip_runtime.h>

// Correlation layer: in1,in2 [8,256,128,128] f32 -> out [8,81,128,128] f32
// out[b, dy*9+dx, y, x] = mean_c in1[b,c,y,x] * in2pad[b,c,y+dy,x+dx], pad=4
//
// v10: TY=16 geometry (staged 24x24 -> in2 requests 403->302 MB) with ZERO
// register pipeline state: in1 also staged via global_load_lds (16KB/step),
// convert pass builds bf16 frags for BOTH operands (F swizzled by kb to kill
// the 4-way MFMA bank conflict; FA gives afrag as one ds_read_b128).
// F/FA single-buffered (MFMA(c) at region A of step 2c+1; first overwrite in
// region B same step, across the barrier). S2/S1 double-buffered.
// Two-rendezvous schedule, per-wave keep vmcnt(7)/vmcnt(6).

#define B_   8
#define C_   256
#define H_   128
#define W_   128
#define ND   9
#define TY   16
#define TW   16
#define CS   (H_ * W_)
#define NST  16                  // 16-ch steps per tile
#define SB2  9216                // floats per S2 half (16*24*24)
#define S1OFF 73728
#define FOFF  106496
#define FAOFF 143360
#define LDS_TOTAL 159744

typedef short v8s __attribute__((ext_vector_type(8)));
typedef float v4f __attribute__((ext_vector_type(4)));

__device__ __forceinline__ unsigned short f2bf(float f) {
    union { float f; unsigned u; } v; v.f = f;
    return (unsigned short)((v.u + 0x7FFFu + ((v.u >> 16) & 1u)) >> 16);
}

__device__ __forceinline__ void dma16(const float* g, void* lds) {
    __builtin_amdgcn_global_load_lds(
        (const __attribute__((address_space(1))) void*)g,
        (__attribute__((address_space(3))) void*)lds, 16, 0, 0);
}

#define FENCE()     asm volatile("" ::: "memory")
// retire G(s+1), keep G(s+2) in flight: per-wave op count 7 (w<4) / 6 (w>=4)
#define WAITK_BAR() do {                                                          \
        if (w < 4) asm volatile("s_waitcnt vmcnt(7)\n\ts_barrier" ::: "memory");  \
        else       asm volatile("s_waitcnt vmcnt(6)\n\ts_barrier" ::: "memory");  \
    } while (0)
#define WAITV0_BAR() asm volatile("s_waitcnt vmcnt(0)\n\ts_barrier" ::: "memory")
#define LGKM0_BAR()  asm volatile("s_waitcnt lgkmcnt(0)\n\ts_barrier" ::: "memory")
#define LGKM0()      asm volatile("s_waitcnt lgkmcnt(0)" ::: "memory")

__global__ __launch_bounds__(512, 2)
void corr_mfma_kernel(const float* __restrict__ in1,
                      const float* __restrict__ in2,
                      float* __restrict__ out) {
    extern __shared__ __align__(16) char ldsbase[];
    float* S2 = (float*)ldsbase;               // [2][16ch][24r][24j] f32
    float* S1 = (float*)(ldsbase + S1OFF);     // [2][16ch][16r][16x] f32
    short* F  = (short*)(ldsbase + FOFF);      // [4kb][576 rj^swz][8e] bf16
    short* FA = (short*)(ldsbase + FAOFF);     // [16r][16px][32ch] bf16
    float* EP = (float*)ldsbase;               // epilogue alias (S2 free then)

    const int tid  = threadIdx.x;
    const int lane = tid & 63;
    const int w    = tid >> 6;

    const int lin = blockIdx.x;                // 512 blocks
    const int b   = lin & 7;                   // batch == XCD
    const int idx = lin >> 3;                  // 0..63
    const int x0  = (idx & 7) * TW;
    const int y0  = (idx >> 3) * TY;

    const int i_px = lane & 15;
    const int kb   = lane >> 4;

    // ---- in2 DMA descriptors: 36 granule-instr; waves 0-3: 5, waves 4-7: 4 ----
    const float* dsrc[5];
    int ddst[5];
    #pragma unroll
    for (int t = 0; t < 5; ++t) {
        if (w >= 4 && t >= 4) { dsrc[t] = in2; ddst[t] = 0; continue; }
        const int q   = (w < 4) ? (w * 5 + t) : (20 + (w - 4) * 4 + t); // 0..35
        const int g   = q * 64 + lane;         // 0..2303
        const int ccl = g / 144;               // channel within 16-ch step
        const int rem = g % 144;
        const int r   = rem / 6;               // staged row 0..23
        const int jg  = rem % 6;               // 4-col granule
        int gy = y0 - 4 + r;
        int gx = x0 - 4 + jg * 4;
        gy = gy < 0 ? 0 : (gy > H_ - 1 ? H_ - 1 : gy);
        gx = gx < 0 ? 0 : (gx > W_ - 4 ? W_ - 4 : gx);   // pad=4 == granule
        dsrc[t] = in2 + ((long)(b * C_) + ccl) * CS + gy * W_ + gx;
        ddst[t] = q * 1024;
    }
    // ---- in1 DMA descriptors: 16 granule-instr, 2/wave ----
    const float* d1src[2];
    int d1dst[2];
    #pragma unroll
    for (int t = 0; t < 2; ++t) {
        const int q   = w * 2 + t;             // 0..15
        const int g   = q * 64 + lane;         // 0..1023
        const int ch  = g >> 6;                // 0..15
        const int rem = g & 63;
        const int r   = rem >> 2;
        const int xg  = rem & 3;
        d1src[t] = in1 + ((long)(b * C_) + ch) * CS + (y0 + r) * W_ + x0 + xg * 4;
        d1dst[t] = q * 1024;
    }

    // ---- convert descriptors ----
    int rem_i[3], kbl_i[3];                    // in2: 1152 items/step
    bool cval[3];
    #pragma unroll
    for (int it = 0; it < 3; ++it) {
        const int s2  = (tid + it * 512) % 1152;
        kbl_i[it] = s2 / 576;
        rem_i[it] = s2 % 576;                  // r*24+j
        const int r = rem_i[it] / 24, j = rem_i[it] % 24;
        cval[it] = ((unsigned)(y0 - 4 + r) < (unsigned)H_) &&
                   ((unsigned)(x0 - 4 + j) < (unsigned)W_);
    }
    const int r1  = tid >> 5;                  // in1: 512 items/step, 1/thread
    const int px1 = (tid >> 1) & 15;
    const int kb1 = tid & 1;

    v4f acc0[2][ND];
    v4f acc1[2][5];
    #pragma unroll
    for (int rw = 0; rw < 2; ++rw) {
        #pragma unroll
        for (int d = 0; d < ND; ++d) acc0[rw][d] = (v4f)0.0f;
        #pragma unroll
        for (int p = 0; p < 5; ++p)  acc1[rw][p] = (v4f)0.0f;
    }

#define ISSUE_G(s_) do {                                                      \
        const long so = (long)(s_) * 16 * CS;                                 \
        char* sb2 = (char*)S2 + ((s_) & 1) * 36864;                           \
        _Pragma("unroll")                                                     \
        for (int t = 0; t < 5; ++t)                                           \
            if (w < 4 || t < 4) dma16(dsrc[t] + so, sb2 + ddst[t]);           \
        char* sb1 = (char*)S1 + ((s_) & 1) * 16384;                           \
        _Pragma("unroll")                                                     \
        for (int t = 0; t < 2; ++t) dma16(d1src[t] + so, sb1 + d1dst[t]);     \
        FENCE();                                                              \
    } while (0)

    // F swizzle: shorts offset = kb32*4608 + (rj ^ (kb32<<1))*8
#define CONVERT(s_) do {                                                      \
        const float* sb2 = S2 + ((s_) & 1) * SB2;                             \
        _Pragma("unroll")                                                     \
        for (int it = 0; it < 3; ++it) {                                      \
            if (it < 2 || tid < 128) {                                        \
                v8s pk;                                                       \
                _Pragma("unroll")                                             \
                for (int e = 0; e < 8; ++e)                                   \
                    pk[e] = (short)f2bf(sb2[kbl_i[it] * 4608 + rem_i[it] + e * 576]); \
                if (!cval[it]) pk = (v8s)0;                                   \
                const int kb32 = ((s_) & 1) * 2 + kbl_i[it];                  \
                *(v8s*)&F[kb32 * 4608 + ((rem_i[it] ^ (kb32 << 1)) << 3)] = pk; \
            }                                                                 \
        }                                                                     \
        const float* sb1 = S1 + ((s_) & 1) * 4096;                            \
        v8s pa;                                                               \
        _Pragma("unroll")                                                     \
        for (int e = 0; e < 8; ++e)                                           \
            pa[e] = (short)f2bf(sb1[(kb1 * 8 + e) * 256 + r1 * 16 + px1]);    \
        *(v8s*)&FA[r1 * 512 + px1 * 32 + ((s_) & 1) * 16 + kb1 * 8] = pa;     \
    } while (0)

    // ---- prologue ----
    ISSUE_G(0);
    ISSUE_G(1);
    WAITK_BAR();                   // all waves' step-0 DMA landed; G(1) in flight
    CONVERT(0);
    LGKM0_BAR();                   // lo halves of F/FA visible; S[0] free

    // ---- main: 16 steps ----
    #pragma unroll
    for (int s = 0; s < NST; ++s) {
        // region A: issue step s+2; MFMA chunk s>>1 on odd steps
        if (s + 2 < NST) ISSUE_G(s + 2);

        if (s & 1) {
            const v8s af0 = *(const v8s*)&FA[(2 * w + 0) * 512 + i_px * 32 + kb * 8];
            const v8s af1 = *(const v8s*)&FA[(2 * w + 1) * 512 + i_px * 32 + kb * 8];
            #pragma unroll
            for (int u = 0; u < 10; ++u) {     // tile0: rolling over r=2w+u
                const int rj = (2 * w + u) * 24 + i_px;
                const v8s f = *(const v8s*)&F[kb * 4608 + ((rj ^ (kb << 1)) << 3)];
                if (u < 9)
                    acc0[0][u] = __builtin_amdgcn_mfma_f32_16x16x32_bf16(
                        af0, f, acc0[0][u], 0, 0, 0);
                if (u > 0)
                    acc0[1][u - 1] = __builtin_amdgcn_mfma_f32_16x16x32_bf16(
                        af1, f, acc0[1][u - 1], 0, 0, 0);
            }
            const int hi = i_px >> 3, j1 = 16 + (i_px & 7);
            #pragma unroll
            for (int u = 0; u < 10; ++u) {     // tile1 packed: 2 dy per MFMA
                int r = 2 * w + hi + u;
                if (r > 23) r = 23;            // (rw1,P4,hi1) garbage, unused
                const int rj = r * 24 + j1;
                const v8s f = *(const v8s*)&F[kb * 4608 + ((rj ^ (kb << 1)) << 3)];
                if ((u & 1) == 0)
                    acc1[0][u >> 1] = __builtin_amdgcn_mfma_f32_16x16x32_bf16(
                        af0, f, acc1[0][u >> 1], 0, 0, 0);
                else
                    acc1[1][u >> 1] = __builtin_amdgcn_mfma_f32_16x16x32_bf16(
                        af1, f, acc1[1][u >> 1], 0, 0, 0);
            }
        }

        // rendezvous: retire G(s+1), keep G(s+2) in flight
        if (s + 2 < NST)       { WAITK_BAR(); }
        else if (s == NST - 2) { WAITV0_BAR(); }

        // region B: convert step s+1
        if (s < NST - 1) {
            CONVERT(s + 1);
            LGKM0_BAR();
        }
    }

    // ---- epilogue: 2 rows/wave, wave-private EP scratch (aliases S2) ----
    float* epw = EP + w * 384;
    const int g4 = lane >> 4;
    #pragma unroll
    for (int rw = 0; rw < 2; ++rw) {
        const int orow = y0 + 2 * w + rw;
        #pragma unroll
        for (int dy = 0; dy < ND; ++dy) {
            #pragma unroll
            for (int q = 0; q < 4; ++q)
                epw[(g4 * 4 + q) * 24 + i_px] = acc0[rw][dy][q];
            if ((i_px >> 3) == (dy & 1)) {
                #pragma unroll
                for (int q = 0; q < 4; ++q)
                    epw[(g4 * 4 + q) * 24 + 16 + (i_px & 7)] = acc1[rw][dy >> 1][q];
            }
            LGKM0();
            #pragma unroll
            for (int rep = 0; rep < 3; ++rep) {
                const int dx = g4 + rep * 4;
                if (dx < 9) {
                    const float v = epw[i_px * 24 + i_px + dx] * (1.0f / 256.0f);
                    out[(((long)b * 81 + dy * 9 + dx) * H_ + orow) * W_ + x0 + i_px] = v;
                }
            }
            LGKM0();
        }
    }
#undef ISSUE_G
#undef CONVERT
}

extern "C" void kernel_launch(void* const* d_in, const int* in_sizes, int n_in,
                              void* d_out, int out_size, void* d_ws, size_t ws_size,
                              hipStream_t stream) {
    const float* in1 = (const float*)d_in[0];
    const float* in2 = (const float*)d_in[1];
    float* outp      = (float*)d_out;
    (void)hipFuncSetAttribute((const void*)corr_mfma_kernel,
                              hipFuncAttributeMaxDynamicSharedMemorySize,
                              LDS_TOTAL);
    corr_mfma_kernel<<<512, 512, LDS_TOTAL, stream>>>(in1, in2, outp);
}

// Round 11
// 90.264 us; speedup vs baseline: 1.7134x; 1.0051x over previous
//
#include <hip/hip_runtime.h>

// Correlation layer: in1,in2 [8,256,128,128] f32 -> out [8,81,128,128] f32
// out[b, dy*9+dx, y, x] = mean_c in1[b,c,y,x] * in2pad[b,c,y+dy,x+dx], pad=4
//
// v11 = v10 with the kb-XOR swizzle REMOVED: the unswizzled F read is a 4-way
// same-address broadcast (free) + 2-way contiguous aliasing (free); the swizzle
// had doubled SQ_LDS_BANK_CONFLICT (1.49M -> 3.33M). Everything else identical:
// TY=16 tile, in1+in2 both DMA-staged (zero reg pipeline state), F/FA single-
// buffered, S2/S1 double-buffered, two-rendezvous schedule, keep vmcnt(7)/(6).

#define B_   8
#define C_   256
#define H_   128
#define W_   128
#define ND   9
#define TY   16
#define TW   16
#define CS   (H_ * W_)
#define NST  16                  // 16-ch steps per tile
#define SB2  9216                // floats per S2 half (16*24*24)
#define S1OFF 73728
#define FOFF  106496
#define FAOFF 143360
#define LDS_TOTAL 159744

typedef short v8s __attribute__((ext_vector_type(8)));
typedef float v4f __attribute__((ext_vector_type(4)));

__device__ __forceinline__ unsigned short f2bf(float f) {
    union { float f; unsigned u; } v; v.f = f;
    return (unsigned short)((v.u + 0x7FFFu + ((v.u >> 16) & 1u)) >> 16);
}

__device__ __forceinline__ void dma16(const float* g, void* lds) {
    __builtin_amdgcn_global_load_lds(
        (const __attribute__((address_space(1))) void*)g,
        (__attribute__((address_space(3))) void*)lds, 16, 0, 0);
}

#define FENCE()     asm volatile("" ::: "memory")
// retire G(s+1), keep G(s+2) in flight: per-wave op count 7 (w<4) / 6 (w>=4)
#define WAITK_BAR() do {                                                          \
        if (w < 4) asm volatile("s_waitcnt vmcnt(7)\n\ts_barrier" ::: "memory");  \
        else       asm volatile("s_waitcnt vmcnt(6)\n\ts_barrier" ::: "memory");  \
    } while (0)
#define WAITV0_BAR() asm volatile("s_waitcnt vmcnt(0)\n\ts_barrier" ::: "memory")
#define LGKM0_BAR()  asm volatile("s_waitcnt lgkmcnt(0)\n\ts_barrier" ::: "memory")
#define LGKM0()      asm volatile("s_waitcnt lgkmcnt(0)" ::: "memory")

__global__ __launch_bounds__(512, 2)
void corr_mfma_kernel(const float* __restrict__ in1,
                      const float* __restrict__ in2,
                      float* __restrict__ out) {
    extern __shared__ __align__(16) char ldsbase[];
    float* S2 = (float*)ldsbase;               // [2][16ch][24r][24j] f32
    float* S1 = (float*)(ldsbase + S1OFF);     // [2][16ch][16r][16x] f32
    short* F  = (short*)(ldsbase + FOFF);      // [4kb][576 rj][8e] bf16
    short* FA = (short*)(ldsbase + FAOFF);     // [16r][16px][32ch] bf16
    float* EP = (float*)ldsbase;               // epilogue alias (S2 free then)

    const int tid  = threadIdx.x;
    const int lane = tid & 63;
    const int w    = tid >> 6;

    const int lin = blockIdx.x;                // 512 blocks
    const int b   = lin & 7;                   // batch == XCD
    const int idx = lin >> 3;                  // 0..63
    const int x0  = (idx & 7) * TW;
    const int y0  = (idx >> 3) * TY;

    const int i_px = lane & 15;
    const int kb   = lane >> 4;

    // ---- in2 DMA descriptors: 36 granule-instr; waves 0-3: 5, waves 4-7: 4 ----
    const float* dsrc[5];
    int ddst[5];
    #pragma unroll
    for (int t = 0; t < 5; ++t) {
        if (w >= 4 && t >= 4) { dsrc[t] = in2; ddst[t] = 0; continue; }
        const int q   = (w < 4) ? (w * 5 + t) : (20 + (w - 4) * 4 + t); // 0..35
        const int g   = q * 64 + lane;         // 0..2303
        const int ccl = g / 144;               // channel within 16-ch step
        const int rem = g % 144;
        const int r   = rem / 6;               // staged row 0..23
        const int jg  = rem % 6;               // 4-col granule
        int gy = y0 - 4 + r;
        int gx = x0 - 4 + jg * 4;
        gy = gy < 0 ? 0 : (gy > H_ - 1 ? H_ - 1 : gy);
        gx = gx < 0 ? 0 : (gx > W_ - 4 ? W_ - 4 : gx);   // pad=4 == granule
        dsrc[t] = in2 + ((long)(b * C_) + ccl) * CS + gy * W_ + gx;
        ddst[t] = q * 1024;
    }
    // ---- in1 DMA descriptors: 16 granule-instr, 2/wave ----
    const float* d1src[2];
    int d1dst[2];
    #pragma unroll
    for (int t = 0; t < 2; ++t) {
        const int q   = w * 2 + t;             // 0..15
        const int g   = q * 64 + lane;         // 0..1023
        const int ch  = g >> 6;                // 0..15
        const int rem = g & 63;
        const int r   = rem >> 2;
        const int xg  = rem & 3;
        d1src[t] = in1 + ((long)(b * C_) + ch) * CS + (y0 + r) * W_ + x0 + xg * 4;
        d1dst[t] = q * 1024;
    }

    // ---- convert descriptors ----
    int rem_i[3], kbl_i[3];                    // in2: 1152 items/step
    bool cval[3];
    #pragma unroll
    for (int it = 0; it < 3; ++it) {
        const int s2  = (tid + it * 512) % 1152;
        kbl_i[it] = s2 / 576;
        rem_i[it] = s2 % 576;                  // r*24+j
        const int r = rem_i[it] / 24, j = rem_i[it] % 24;
        cval[it] = ((unsigned)(y0 - 4 + r) < (unsigned)H_) &&
                   ((unsigned)(x0 - 4 + j) < (unsigned)W_);
    }
    const int r1  = tid >> 5;                  // in1: 512 items/step, 1/thread
    const int px1 = (tid >> 1) & 15;
    const int kb1 = tid & 1;

    v4f acc0[2][ND];
    v4f acc1[2][5];
    #pragma unroll
    for (int rw = 0; rw < 2; ++rw) {
        #pragma unroll
        for (int d = 0; d < ND; ++d) acc0[rw][d] = (v4f)0.0f;
        #pragma unroll
        for (int p = 0; p < 5; ++p)  acc1[rw][p] = (v4f)0.0f;
    }

#define ISSUE_G(s_) do {                                                      \
        const long so = (long)(s_) * 16 * CS;                                 \
        char* sb2 = (char*)S2 + ((s_) & 1) * 36864;                           \
        _Pragma("unroll")                                                     \
        for (int t = 0; t < 5; ++t)                                           \
            if (w < 4 || t < 4) dma16(dsrc[t] + so, sb2 + ddst[t]);           \
        char* sb1 = (char*)S1 + ((s_) & 1) * 16384;                           \
        _Pragma("unroll")                                                     \
        for (int t = 0; t < 2; ++t) dma16(d1src[t] + so, sb1 + d1dst[t]);     \
        FENCE();                                                              \
    } while (0)

#define CONVERT(s_) do {                                                      \
        const float* sb2 = S2 + ((s_) & 1) * SB2;                             \
        _Pragma("unroll")                                                     \
        for (int it = 0; it < 3; ++it) {                                      \
            if (it < 2 || tid < 128) {                                        \
                v8s pk;                                                       \
                _Pragma("unroll")                                             \
                for (int e = 0; e < 8; ++e)                                   \
                    pk[e] = (short)f2bf(sb2[kbl_i[it] * 4608 + rem_i[it] + e * 576]); \
                if (!cval[it]) pk = (v8s)0;                                   \
                const int kb32 = ((s_) & 1) * 2 + kbl_i[it];                  \
                *(v8s*)&F[kb32 * 4608 + (rem_i[it] << 3)] = pk;               \
            }                                                                 \
        }                                                                     \
        const float* sb1 = S1 + ((s_) & 1) * 4096;                            \
        v8s pa;                                                               \
        _Pragma("unroll")                                                     \
        for (int e = 0; e < 8; ++e)                                           \
            pa[e] = (short)f2bf(sb1[(kb1 * 8 + e) * 256 + r1 * 16 + px1]);    \
        *(v8s*)&FA[r1 * 512 + px1 * 32 + ((s_) & 1) * 16 + kb1 * 8] = pa;     \
    } while (0)

    // ---- prologue ----
    ISSUE_G(0);
    ISSUE_G(1);
    WAITK_BAR();                   // all waves' step-0 DMA landed; G(1) in flight
    CONVERT(0);
    LGKM0_BAR();                   // lo halves of F/FA visible; S[0] free

    // ---- main: 16 steps ----
    #pragma unroll
    for (int s = 0; s < NST; ++s) {
        // region A: issue step s+2; MFMA chunk s>>1 on odd steps
        if (s + 2 < NST) ISSUE_G(s + 2);

        if (s & 1) {
            const v8s af0 = *(const v8s*)&FA[(2 * w + 0) * 512 + i_px * 32 + kb * 8];
            const v8s af1 = *(const v8s*)&FA[(2 * w + 1) * 512 + i_px * 32 + kb * 8];
            #pragma unroll
            for (int u = 0; u < 10; ++u) {     // tile0: rolling over r=2w+u
                const int rj = (2 * w + u) * 24 + i_px;
                const v8s f = *(const v8s*)&F[kb * 4608 + (rj << 3)];
                if (u < 9)
                    acc0[0][u] = __builtin_amdgcn_mfma_f32_16x16x32_bf16(
                        af0, f, acc0[0][u], 0, 0, 0);
                if (u > 0)
                    acc0[1][u - 1] = __builtin_amdgcn_mfma_f32_16x16x32_bf16(
                        af1, f, acc0[1][u - 1], 0, 0, 0);
            }
            const int hi = i_px >> 3, j1 = 16 + (i_px & 7);
            #pragma unroll
            for (int u = 0; u < 10; ++u) {     // tile1 packed: 2 dy per MFMA
                int r = 2 * w + hi + u;
                if (r > 23) r = 23;            // (rw1,P4,hi1) garbage, unused
                const int rj = r * 24 + j1;
                const v8s f = *(const v8s*)&F[kb * 4608 + (rj << 3)];
                if ((u & 1) == 0)
                    acc1[0][u >> 1] = __builtin_amdgcn_mfma_f32_16x16x32_bf16(
                        af0, f, acc1[0][u >> 1], 0, 0, 0);
                else
                    acc1[1][u >> 1] = __builtin_amdgcn_mfma_f32_16x16x32_bf16(
                        af1, f, acc1[1][u >> 1], 0, 0, 0);
            }
        }

        // rendezvous: retire G(s+1), keep G(s+2) in flight
        if (s + 2 < NST)       { WAITK_BAR(); }
        else if (s == NST - 2) { WAITV0_BAR(); }

        // region B: convert step s+1
        if (s < NST - 1) {
            CONVERT(s + 1);
            LGKM0_BAR();
        }
    }

    // ---- epilogue: 2 rows/wave, wave-private EP scratch (aliases S2) ----
    float* epw = EP + w * 384;
    const int g4 = lane >> 4;
    #pragma unroll
    for (int rw = 0; rw < 2; ++rw) {
        const int orow = y0 + 2 * w + rw;
        #pragma unroll
        for (int dy = 0; dy < ND; ++dy) {
            #pragma unroll
            for (int q = 0; q < 4; ++q)
                epw[(g4 * 4 + q) * 24 + i_px] = acc0[rw][dy][q];
            if ((i_px >> 3) == (dy & 1)) {
                #pragma unroll
                for (int q = 0; q < 4; ++q)
                    epw[(g4 * 4 + q) * 24 + 16 + (i_px & 7)] = acc1[rw][dy >> 1][q];
            }
            LGKM0();
            #pragma unroll
            for (int rep = 0; rep < 3; ++rep) {
                const int dx = g4 + rep * 4;
                if (dx < 9) {
                    const float v = epw[i_px * 24 + i_px + dx] * (1.0f / 256.0f);
                    out[(((long)b * 81 + dy * 9 + dx) * H_ + orow) * W_ + x0 + i_px] = v;
                }
            }
            LGKM0();
        }
    }
#undef ISSUE_G
#undef CONVERT
}

extern "C" void kernel_launch(void* const* d_in, const int* in_sizes, int n_in,
                              void* d_out, int out_size, void* d_ws, size_t ws_size,
                              hipStream_t stream) {
    const float* in1 = (const float*)d_in[0];
    const float* in2 = (const float*)d_in[1];
    float* outp      = (float*)d_out;
    (void)hipFuncSetAttribute((const void*)corr_mfma_kernel,
                              hipFuncAttributeMaxDynamicSharedMemorySize,
                              LDS_TOTAL);
    corr_mfma_kernel<<<512, 512, LDS_TOTAL, stream>>>(in1, in2, outp);
}